// Round 4
// baseline (1274.310 us; speedup 1.0000x reference)
//
#include <hip/hip_runtime.h>

#define D_IN 1024
#define HID  2048
#define KSEL 32

typedef __attribute__((ext_vector_type(8))) short short8;
typedef __attribute__((ext_vector_type(4))) float f32x4;

__device__ __forceinline__ short f2bf(float f) {
  union { float f; unsigned u; } c; c.f = f;
  unsigned u = c.u;
  unsigned r = (u + 0x7fffu + ((u >> 16) & 1u)) >> 16;  // RNE
  return (short)(r & 0xffffu);
}

__device__ __forceinline__ void load_lds16(const void* g, void* l) {
  __builtin_amdgcn_global_load_lds((const __attribute__((address_space(1))) void*)g,
                                   (__attribute__((address_space(3))) void*)l,
                                   16, 0, 0);
}

// ---------------------------------------------------------------------------
// Pre-pass 1 (unchanged, proven): x (2048x1024 fp32) -> bf16 A-panels:
// Apanel[mt][ks][m(128)][k(32)]
// ---------------------------------------------------------------------------
__global__ __launch_bounds__(256) void conv_x_kernel(const float* __restrict__ x,
                                                     short* __restrict__ Apanel) {
  int tid = blockIdx.x * 256 + threadIdx.x;   // 0..262143, each does 8 elems
  int k8 = tid & 3;
  int m  = (tid >> 2) & 127;
  int ks = (tid >> 9) & 31;
  int mt = tid >> 14;
  const float* src = x + (size_t)(mt * 128 + m) * D_IN + ks * 32 + k8 * 8;
  short8 v;
#pragma unroll
  for (int j = 0; j < 8; ++j) v[j] = f2bf(src[j]);
  *(short8*)(Apanel + (size_t)tid * 8) = v;   // offset == tid*8 by construction
}

// ---------------------------------------------------------------------------
// Pre-pass 2 (unchanged from R2, proven): one block per (kk, ks, nt); stage
// 32d x 128h fp32 (16 KB LDS), one barrier, column-read + f2bf + contiguous
// short8 write. Output: Bpanel[kk][nt][ks][n(128)][d(32)].
// ---------------------------------------------------------------------------
__global__ __launch_bounds__(256) void conv_w1_kernel(const float* __restrict__ W1,
                                                      const int* __restrict__ subset,
                                                      short* __restrict__ Bpanel) {
  int bid = blockIdx.x;            // 16384 = kk(32) * ks(32) * nt(16)
  int nt = bid & 15;
  int ks = (bid >> 4) & 31;
  int kk = bid >> 9;
  int p  = subset[kk];

  __shared__ __align__(16) float tile[32][128];   // 16 KB, rows contiguous
  int t = threadIdx.x;
  int wave = t >> 6, lane = t & 63;

  const float* src = W1 + ((size_t)p * D_IN + ks * 32) * HID + nt * 128;
#pragma unroll
  for (int rr = 0; rr < 4; ++rr) {
    int row = rr * 8 + wave * 2;                 // wave-uniform, covers {row,row+1}
    const float* g = src + (size_t)(row + (lane >> 5)) * HID + (lane & 31) * 4;
    load_lds16(g, &tile[row][0]);
  }
  __syncthreads();

  int n  = t >> 1;
  int kh = (t & 1) * 16;
  short8 v0, v1;
#pragma unroll
  for (int dd = 0; dd < 8; ++dd) v0[dd] = f2bf(tile[kh + dd][n]);
#pragma unroll
  for (int dd = 0; dd < 8; ++dd) v1[dd] = f2bf(tile[kh + 8 + dd][n]);
  short* dst = Bpanel + (((size_t)(kk * 16 + nt) * 32) + ks) * 4096 + n * 32 + kh;
  *(short8*)dst       = v0;
  *(short8*)(dst + 8) = v1;
}

// ---------------------------------------------------------------------------
// Init: out[b][k] = b2[subset[k]]  (atomics accumulate on top)
// ---------------------------------------------------------------------------
__global__ __launch_bounds__(256) void init_out_kernel(const int* __restrict__ subset,
                                                       const float* __restrict__ b2,
                                                       float* __restrict__ out) {
  int i = blockIdx.x * 256 + threadIdx.x;  // 65536
  out[i] = b2[subset[i & 31]];
}

// ---------------------------------------------------------------------------
// Main fused GEMM (v2): same tile/fragment/epilogue as the proven kernel, but
// the K-loop is the T3 "minimum 2-phase" pipeline: double-buffered LDS,
// prefetch STAGE(ks+1) issued BEFORE ds_read+MFMA of tile ks, ONE barrier per
// K-step. Load latency hides under compute instead of being fully exposed at
// the vmcnt(0) drain. Buffers are compile-time static (even/odd split).
// ---------------------------------------------------------------------------
__global__ __launch_bounds__(256) void gemm_kernel(const short* __restrict__ Apanel,
                                                   const short* __restrict__ Bpanel,
                                                   const int* __restrict__ subset,
                                                   const float* __restrict__ b1,
                                                   const float* __restrict__ W2,
                                                   float* __restrict__ out) {
  __shared__ __align__(16) short Atile[2][4096];   // 2 x (128 m x 32 k)
  __shared__ __align__(16) short Btile[2][4096];   // 2 x (128 n x 32 k)

  int id = blockIdx.x;
  int xcd = id & 7;
  int chunk = id >> 3;                 // 0..1023
  int kk = xcd * 4 + (chunk >> 8);
  int nt = (chunk >> 4) & 15;
  int mt = chunk & 15;

  int tid  = threadIdx.x;
  int wave = tid >> 6;
  int lane = tid & 63;
  int wm = wave >> 1, wn = wave & 1;   // 2x2 wave grid, 64x64 each
  int ml = lane & 15;
  int kq = lane >> 4;

  const short* Abase = Apanel + (size_t)mt * (32 * 4096);
  const short* Bbase = Bpanel + (size_t)((kk * 16 + nt)) * (32 * 4096);

  int aoff0 = wave * 512;              // shorts; wave-uniform LDS staging base
  int aoff1 = 2048 + wave * 512;

  f32x4 acc[4][4] = {};
  int arow = wm * 64 + ml;
  int brow = wn * 64 + ml;

  auto STAGE = [&](int ksn, short* Ad, short* Bd) {
    const short* ga = Abase + ksn * 4096;
    const short* gb = Bbase + ksn * 4096;
    load_lds16(ga + tid * 8,         Ad + aoff0);
    load_lds16(ga + (256 + tid) * 8, Ad + aoff1);
    load_lds16(gb + tid * 8,         Bd + aoff0);
    load_lds16(gb + (256 + tid) * 8, Bd + aoff1);
  };
  auto COMPUTE = [&](const short* As, const short* Bs) {
    const short8* Ar = (const short8*)As;
    const short8* Br = (const short8*)Bs;
    short8 a[4], b[4];
#pragma unroll
    for (int ti = 0; ti < 4; ++ti) a[ti] = Ar[(arow + ti * 16) * 4 + kq];
#pragma unroll
    for (int tj = 0; tj < 4; ++tj) b[tj] = Br[(brow + tj * 16) * 4 + kq];
#pragma unroll
    for (int ti = 0; ti < 4; ++ti)
#pragma unroll
      for (int tj = 0; tj < 4; ++tj)
        acc[ti][tj] = __builtin_amdgcn_mfma_f32_16x16x32_bf16(a[ti], b[tj],
                                                              acc[ti][tj], 0, 0, 0);
  };

  short* A0 = Atile[0]; short* A1 = Atile[1];
  short* B0 = Btile[0]; short* B1 = Btile[1];

  STAGE(0, A0, B0);
  __syncthreads();

  for (int ks = 0; ks < 31; ++ks) {
    if (ks & 1) { STAGE(ks + 1, A0, B0); COMPUTE(A1, B1); }
    else        { STAGE(ks + 1, A1, B1); COMPUTE(A0, B0); }
    __syncthreads();                  // drains vmcnt: next tile staged
  }
  COMPUTE(A1, B1);                    // tile 31 (staged at ks=30), no barrier

  int sk = subset[kk];
  const float* b1p = b1 + (size_t)sk * HID + nt * 128 + wn * 64;
  const float* w2p = W2 + (size_t)sk * HID + nt * 128 + wn * 64;
  float b1v[4], w2v[4];
#pragma unroll
  for (int tj = 0; tj < 4; ++tj) {
    int n = tj * 16 + ml;
    b1v[tj] = b1p[n];
    w2v[tj] = w2p[n];
  }
  float part[4][4];
#pragma unroll
  for (int ti = 0; ti < 4; ++ti)
#pragma unroll
    for (int r = 0; r < 4; ++r) {
      float s = 0.f;
#pragma unroll
      for (int tj = 0; tj < 4; ++tj) {
        float h = acc[ti][tj][r] + b1v[tj];
        h = h > 0.f ? h : 0.f;
        s += h * w2v[tj];
      }
      part[ti][r] = s;
    }
#pragma unroll
  for (int off = 1; off < 16; off <<= 1) {
#pragma unroll
    for (int ti = 0; ti < 4; ++ti)
#pragma unroll
      for (int r = 0; r < 4; ++r)
        part[ti][r] += __shfl_xor(part[ti][r], off, 64);
  }
  if (ml == 0) {
    int mbase = mt * 128 + wm * 64 + kq * 4;
#pragma unroll
    for (int ti = 0; ti < 4; ++ti)
#pragma unroll
      for (int r = 0; r < 4; ++r)
        atomicAdd(out + (size_t)(mbase + ti * 16 + r) * KSEL + kk, part[ti][r]);
  }
}

// ---------------------------------------------------------------------------
extern "C" void kernel_launch(void* const* d_in, const int* in_sizes, int n_in,
                              void* d_out, int out_size, void* d_ws, size_t ws_size,
                              hipStream_t stream) {
  const float* x      = (const float*)d_in[0];
  const int*   subset = (const int*)d_in[1];
  const float* W1     = (const float*)d_in[2];
  const float* b1     = (const float*)d_in[3];
  const float* W2     = (const float*)d_in[4];
  const float* b2     = (const float*)d_in[5];
  float* out = (float*)d_out;

  short* Apanel = (short*)d_ws;                                    // 4 MiB
  short* Bpanel = (short*)((char*)d_ws + (size_t)4 * 1024 * 1024); // 128 MiB

  conv_x_kernel<<<1024, 256, 0, stream>>>(x, Apanel);
  conv_w1_kernel<<<16384, 256, 0, stream>>>(W1, subset, Bpanel);
  init_out_kernel<<<256, 256, 0, stream>>>(subset, b2, out);
  gemm_kernel<<<8192, 256, 0, stream>>>(Apanel, Bpanel, subset, b1, W2, out);
}

// Round 5
// 886.158 us; speedup vs baseline: 1.4380x; 1.4380x over previous
//
#include <hip/hip_runtime.h>

#define D_IN 1024
#define HID  2048
#define KSEL 32

typedef __attribute__((ext_vector_type(8))) short short8;
typedef __attribute__((ext_vector_type(4))) float f32x4;

__device__ __forceinline__ short f2bf(float f) {
  union { float f; unsigned u; } c; c.f = f;
  unsigned u = c.u;
  unsigned r = (u + 0x7fffu + ((u >> 16) & 1u)) >> 16;  // RNE
  return (short)(r & 0xffffu);
}

__device__ __forceinline__ void load_lds16(const void* g, void* l) {
  __builtin_amdgcn_global_load_lds((const __attribute__((address_space(1))) void*)g,
                                   (__attribute__((address_space(3))) void*)l,
                                   16, 0, 0);
}

// ---------------------------------------------------------------------------
// Pre-pass 1: x (2048x1024 fp32) -> bf16 A-panels for the 256x256 gemm:
// Apanel[mt(8)][kt(16)][ks2(2)][m(256)][k(32)], contiguous == tid*8 order.
// ---------------------------------------------------------------------------
__global__ __launch_bounds__(256) void conv_x_kernel(const float* __restrict__ x,
                                                     short* __restrict__ Apanel) {
  int tid = blockIdx.x * 256 + threadIdx.x;   // 0..262143, each does 8 elems
  int k8  = tid & 3;
  int m   = (tid >> 2) & 255;
  int ks2 = (tid >> 10) & 1;
  int kt  = (tid >> 11) & 15;
  int mt  = tid >> 15;
  const float* src = x + (size_t)(mt * 256 + m) * D_IN + kt * 64 + ks2 * 32 + k8 * 8;
  short8 v;
#pragma unroll
  for (int j = 0; j < 8; ++j) v[j] = f2bf(src[j]);
  *(short8*)(Apanel + (size_t)tid * 8) = v;   // offset == tid*8 by construction
}

// ---------------------------------------------------------------------------
// Pre-pass 2 (proven R2 structure, remapped output): one block per
// (kk, dg, hg): stage 32d x 128h fp32 (16 KB LDS), one barrier, column-read +
// f2bf + contiguous short8 write.
// Output: Bpanel[kk(32)][nt(8)][kt(16)][ks2(2)][n(256)][d(32)], dg = kt*2+ks2,
// hg indexes 128-h halves (nt = hg>>1, nh = hg&1).
// ---------------------------------------------------------------------------
__global__ __launch_bounds__(256) void conv_w1_kernel(const float* __restrict__ W1,
                                                      const int* __restrict__ subset,
                                                      short* __restrict__ Bpanel) {
  int bid = blockIdx.x;            // 16384 = kk(32) * dg(32) * hg(16)
  int hg = bid & 15;
  int dg = (bid >> 4) & 31;
  int kk = bid >> 9;
  int p  = subset[kk];
  int nt = hg >> 1;
  int nh = hg & 1;

  __shared__ __align__(16) float tile[32][128];   // 16 KB, rows contiguous
  int t = threadIdx.x;
  int wave = t >> 6, lane = t & 63;

  const float* src = W1 + ((size_t)p * D_IN + dg * 32) * HID + hg * 128;
#pragma unroll
  for (int rr = 0; rr < 4; ++rr) {
    int row = rr * 8 + wave * 2;                 // wave-uniform, covers {row,row+1}
    const float* g = src + (size_t)(row + (lane >> 5)) * HID + (lane & 31) * 4;
    load_lds16(g, &tile[row][0]);
  }
  __syncthreads();

  int n  = t >> 1;                 // 0..127
  int kh = (t & 1) * 16;           // 0 or 16
  short8 v0, v1;
#pragma unroll
  for (int dd = 0; dd < 8; ++dd) v0[dd] = f2bf(tile[kh + dd][n]);
#pragma unroll
  for (int dd = 0; dd < 8; ++dd) v1[dd] = f2bf(tile[kh + 8 + dd][n]);
  short* dst = Bpanel + (((size_t)(kk * 8 + nt) * 32) + dg) * 8192
             + (nh * 128 + n) * 32 + kh;
  *(short8*)dst       = v0;
  *(short8*)(dst + 8) = v1;
}

// ---------------------------------------------------------------------------
// Init: out[b][k] = b2[subset[k]]  (atomics accumulate on top)
// ---------------------------------------------------------------------------
__global__ __launch_bounds__(256) void init_out_kernel(const int* __restrict__ subset,
                                                       const float* __restrict__ b2,
                                                       float* __restrict__ out) {
  int i = blockIdx.x * 256 + threadIdx.x;  // 65536
  out[i] = b2[subset[i & 31]];
}

// ---------------------------------------------------------------------------
// Main fused GEMM: 8-phase 256x256 schedule (T3+T4+T5). 512 threads = 8 waves
// (2M x 4N), per-wave 128x64 output (8x4 16x16 frags). LDS = 2 slots x 4 units
// {A-ks2=0, A-ks2=1, B-ks2=0, B-ks2=1} of 256x32 bf16 (16 KB) = 128 KB.
// Iter = 2 K-tiles (BK=64 each): phases (ks2, mh) per tile; per phase:
// ds_reads (4 A + 4 B on ks2-entry), 1 unit prefetch (2 global_load_lds),
// counted vmcnt(4) at even phases (never 0), raw s_barrier, setprio around
// 16 MFMA. Fragment/epilogue indexing identical to the proven R0 patterns.
// ---------------------------------------------------------------------------
__global__ __launch_bounds__(512, 2) void gemm_kernel(const short* __restrict__ Apanel,
                                                      const short* __restrict__ Bpanel,
                                                      const int* __restrict__ subset,
                                                      const float* __restrict__ b1,
                                                      const float* __restrict__ W2,
                                                      float* __restrict__ out) {
  __shared__ __align__(16) short lds[2][4][8192];   // [slot][A0,A1,B0,B1][256*32]

  int id = blockIdx.x;                 // 2048 = 8 xcd * 256
  int xcd = id & 7;
  int chunk = id >> 3;                 // 0..255
  int kk = xcd * 4 + (chunk >> 6);
  int rem = chunk & 63;
  int nt = rem >> 3;                   // 0..7
  int mt = rem & 7;                    // 0..7

  int tid  = threadIdx.x;
  int wave = tid >> 6;
  int lane = tid & 63;
  int wm = wave >> 2, wn = wave & 3;   // 2x4 wave grid: 128m x 64n each
  int ml = lane & 15;
  int kq = lane >> 4;

  const short* Abase = Apanel + (size_t)mt * (16 * 2 * 8192);
  const short* Bbase = Bpanel + (size_t)(kk * 8 + nt) * (16 * 2 * 8192);

#define AU(kt, ks2) (Abase + (((kt) * 2 + (ks2)) << 13))
#define BU(kt, ks2) (Bbase + (((kt) * 2 + (ks2)) << 13))

#define STAGE_UNIT(SLOT, UNIT, GSRC) do {                                  \
    const short* _g = (GSRC) + tid * 8;                                    \
    load_lds16(_g,        &lds[SLOT][UNIT][wave * 512]);                   \
    load_lds16(_g + 4096, &lds[SLOT][UNIT][wave * 512 + 4096]);            \
  } while (0)

  f32x4 acc[8][4] = {};
  short8 a[4], b[4];

  int arow0 = wm * 128 + ml;           // + mf*16
  int brow0 = wn * 64 + ml;            // + nf*16

  // PHASE(CS = compute slot, K2 = ks2, MH = m-half, SS/SU = stage slot/unit,
  //       SG = stage source, DOB = load b-frags, DOVM = counted vmcnt)
#define PHASE(CS, K2, MH, SS, SU, SG, DOB, DOVM) do {                      \
    const short* _ua = &lds[CS][K2][0];                                    \
    _Pragma("unroll")                                                      \
    for (int q = 0; q < 4; ++q)                                            \
      a[q] = *(const short8*)(_ua + ((arow0 + (MH * 4 + q) * 16) * 4 + kq) * 8); \
    if (DOB) {                                                             \
      const short* _ub = &lds[CS][2 + K2][0];                              \
      _Pragma("unroll")                                                    \
      for (int q = 0; q < 4; ++q)                                          \
        b[q] = *(const short8*)(_ub + ((brow0 + q * 16) * 4 + kq) * 8);    \
    }                                                                      \
    STAGE_UNIT(SS, SU, SG);                                                \
    __builtin_amdgcn_sched_barrier(0);                                     \
    if (DOVM) asm volatile("s_waitcnt vmcnt(4)" ::: "memory");             \
    __builtin_amdgcn_s_barrier();                                          \
    __builtin_amdgcn_sched_barrier(0);                                     \
    __builtin_amdgcn_s_setprio(1);                                         \
    _Pragma("unroll")                                                      \
    for (int i = 0; i < 4; ++i)                                            \
      _Pragma("unroll")                                                    \
      for (int j = 0; j < 4; ++j)                                          \
        acc[MH * 4 + i][j] = __builtin_amdgcn_mfma_f32_16x16x32_bf16(      \
            a[i], b[j], acc[MH * 4 + i][j], 0, 0, 0);                      \
    __builtin_amdgcn_s_setprio(0);                                         \
    __builtin_amdgcn_sched_barrier(0);                                     \
  } while (0)

  // Prologue: stage tile 0's 4 units; confirm A0,B0; enter uniform loop.
  STAGE_UNIT(0, 0, AU(0, 0));
  STAGE_UNIT(0, 2, BU(0, 0));
  STAGE_UNIT(0, 1, AU(0, 1));
  STAGE_UNIT(0, 3, BU(0, 1));
  __builtin_amdgcn_sched_barrier(0);
  asm volatile("s_waitcnt vmcnt(4)" ::: "memory");
  __builtin_amdgcn_s_barrier();
  __builtin_amdgcn_sched_barrier(0);

  for (int t2 = 0; t2 < 8; ++t2) {
    int ktA = 2 * t2 + 1;                    // staged into slot1 during P1-P4
    int ktB = (t2 < 7) ? 2 * t2 + 2 : 15;    // staged into slot0 during P5-P8
    // P1..P4: compute tile 2*t2 (slot 0)
    PHASE(0, 0, 0, 1, 0, AU(ktA, 0), 1, 0);
    PHASE(0, 0, 1, 1, 2, BU(ktA, 0), 0, 1);
    PHASE(0, 1, 0, 1, 1, AU(ktA, 1), 1, 0);
    PHASE(0, 1, 1, 1, 3, BU(ktA, 1), 0, 1);
    // P5..P8: compute tile 2*t2+1 (slot 1)
    PHASE(1, 0, 0, 0, 0, AU(ktB, 0), 1, 0);
    PHASE(1, 0, 1, 0, 2, BU(ktB, 0), 0, 1);
    PHASE(1, 1, 0, 0, 1, AU(ktB, 1), 1, 0);
    PHASE(1, 1, 1, 0, 3, BU(ktB, 1), 0, 1);
  }
  asm volatile("s_waitcnt vmcnt(0)" ::: "memory");   // drain clamped prefetch

  // Epilogue (R0-proven math on 8x4 frags): relu(acc + b1) . W2, reduce over
  // n within 16-lane group, atomicAdd per (m, kk).
  int sk = subset[kk];
  const float* b1p = b1 + (size_t)sk * HID + nt * 256 + wn * 64;
  const float* w2p = W2 + (size_t)sk * HID + nt * 256 + wn * 64;
  float b1v[4], w2v[4];
#pragma unroll
  for (int nf = 0; nf < 4; ++nf) {
    int n = nf * 16 + ml;
    b1v[nf] = b1p[n];
    w2v[nf] = w2p[n];
  }
  float part[8][4];
#pragma unroll
  for (int mf = 0; mf < 8; ++mf)
#pragma unroll
    for (int r = 0; r < 4; ++r) {
      float s = 0.f;
#pragma unroll
      for (int nf = 0; nf < 4; ++nf) {
        float h = acc[mf][nf][r] + b1v[nf];
        h = h > 0.f ? h : 0.f;
        s += h * w2v[nf];
      }
      part[mf][r] = s;
    }
#pragma unroll
  for (int off = 1; off < 16; off <<= 1) {
#pragma unroll
    for (int mf = 0; mf < 8; ++mf)
#pragma unroll
      for (int r = 0; r < 4; ++r)
        part[mf][r] += __shfl_xor(part[mf][r], off, 64);
  }
  if (ml == 0) {
    int mbase = mt * 256 + wm * 128 + kq * 4;
#pragma unroll
    for (int mf = 0; mf < 8; ++mf)
#pragma unroll
      for (int r = 0; r < 4; ++r)
        atomicAdd(out + (size_t)(mbase + mf * 16 + r) * KSEL + kk, part[mf][r]);
  }
#undef PHASE
#undef STAGE_UNIT
#undef AU
#undef BU
}

// ---------------------------------------------------------------------------
extern "C" void kernel_launch(void* const* d_in, const int* in_sizes, int n_in,
                              void* d_out, int out_size, void* d_ws, size_t ws_size,
                              hipStream_t stream) {
  const float* x      = (const float*)d_in[0];
  const int*   subset = (const int*)d_in[1];
  const float* W1     = (const float*)d_in[2];
  const float* b1     = (const float*)d_in[3];
  const float* W2     = (const float*)d_in[4];
  const float* b2     = (const float*)d_in[5];
  float* out = (float*)d_out;

  short* Apanel = (short*)d_ws;                                    // 4 MiB
  short* Bpanel = (short*)((char*)d_ws + (size_t)4 * 1024 * 1024); // 128 MiB

  conv_x_kernel<<<1024, 256, 0, stream>>>(x, Apanel);
  conv_w1_kernel<<<16384, 256, 0, stream>>>(W1, subset, Bpanel);
  init_out_kernel<<<256, 256, 0, stream>>>(subset, b2, out);
  gemm_kernel<<<2048, 512, 0, stream>>>(Apanel, Bpanel, subset, b1, W2, out);
}